// Round 4
// baseline (457.819 us; speedup 1.0000x reference)
//
#include <hip/hip_runtime.h>
#include <cstdint>
#include <cstddef>

// Problem constants: B=4, S=1024, D=1024, H=16, DK=64, DV=32. FP32 I/O.
#define BB 4
#define SS 1024
#define DD 1024
#define HH 16
#define DKK 64
#define DVV 32
#define LOG2E 1.44269504088896340736f

typedef __bf16 bf16_t;
typedef __bf16 bf16x8 __attribute__((ext_vector_type(8)));
typedef float f32x4 __attribute__((ext_vector_type(4)));

typedef __attribute__((address_space(3))) unsigned int lds_u32;
typedef const __attribute__((address_space(1))) unsigned int glb_u32;

// load 8 consecutive fp32, convert to 8 bf16 (RNE via __bf16 cast)
__device__ inline bf16x8 cvt8(const float* __restrict__ s) {
  float4 a = *(const float4*)s;
  float4 b = *(const float4*)(s + 4);
  bf16x8 r;
  r[0] = (__bf16)a.x; r[1] = (__bf16)a.y; r[2] = (__bf16)a.z; r[3] = (__bf16)a.w;
  r[4] = (__bf16)b.x; r[5] = (__bf16)b.y; r[6] = (__bf16)b.z; r[7] = (__bf16)b.w;
  return r;
}

// ---------------------------------------------------------------------------
// X fp32 -> bf16, 4096x1024. grid 1024, 256 threads, 16 elems/thread.
// ---------------------------------------------------------------------------
__global__ __launch_bounds__(256) void xcvt_kernel(
    const float* __restrict__ X, bf16_t* __restrict__ Xb) {
  size_t i = ((size_t)blockIdx.x * 256 + threadIdx.x) * 16;
  bf16x8 a = cvt8(X + i);
  bf16x8 b = cvt8(X + i + 8);
  *(bf16x8*)(Xb + i) = a;
  *(bf16x8*)(Xb + i + 8) = b;
}

// ---------------------------------------------------------------------------
// Generic transpose + cvt (used for Wo): dst[n][m] = (bf16) src[m][n].
// grid (ceil(N/64), M/64), 256 threads.
// ---------------------------------------------------------------------------
__global__ __launch_bounds__(256) void transpose_cvt_kernel(
    const float* __restrict__ src, bf16_t* __restrict__ dst,
    int M, int N, size_t srcStride, size_t dstStride) {
  __shared__ __align__(16) bf16_t T[64][72];
  const int tid = threadIdx.x;
  const int n0 = blockIdx.x * 64, m0 = blockIdx.y * 64;
  const float* s = src + (size_t)blockIdx.z * srcStride;
  bf16_t* d = dst + (size_t)blockIdx.z * dstStride;
  const int rr = tid >> 3, c8 = (tid & 7) * 8;

  if (n0 + c8 < N) {
#pragma unroll
    for (int mm = rr; mm < 64; mm += 32) {
      const float* p = s + (size_t)(m0 + mm) * N + n0 + c8;
      float4 a = *(const float4*)p;
      float4 b = *(const float4*)(p + 4);
      T[c8 + 0][mm] = (__bf16)a.x; T[c8 + 1][mm] = (__bf16)a.y;
      T[c8 + 2][mm] = (__bf16)a.z; T[c8 + 3][mm] = (__bf16)a.w;
      T[c8 + 4][mm] = (__bf16)b.x; T[c8 + 5][mm] = (__bf16)b.y;
      T[c8 + 6][mm] = (__bf16)b.z; T[c8 + 7][mm] = (__bf16)b.w;
    }
  }
  __syncthreads();
#pragma unroll
  for (int rn = rr; rn < 64; rn += 32) {
    if (n0 + rn < N)
      *(uint4*)(d + (size_t)(n0 + rn) * M + m0 + c8) = *(uint4*)&T[rn][c8];
  }
}

// ---------------------------------------------------------------------------
// Merged Wq/Wk/Wv transpose into WcatT[2560][1024] bf16.
// grid (16, 48): y<16 -> Wq head y; y<32 -> Wk; else Wv (N=32).
// ---------------------------------------------------------------------------
__global__ __launch_bounds__(256) void wqkv_transpose_kernel(
    const float* __restrict__ Wq, const float* __restrict__ Wk,
    const float* __restrict__ Wv, bf16_t* __restrict__ WcatT) {
  __shared__ __align__(16) bf16_t T[64][72];
  const int tid = threadIdx.x;
  const int z = blockIdx.y;
  const float* s; bf16_t* d; int N;
  if (z < 16)      { s = Wq + (size_t)z * 65536;        d = WcatT + (size_t)z * 65536;                          N = 64; }
  else if (z < 32) { s = Wk + (size_t)(z - 16) * 65536; d = WcatT + (size_t)1024 * 1024 + (size_t)(z - 16) * 65536; N = 64; }
  else             { s = Wv + (size_t)(z - 32) * 32768; d = WcatT + (size_t)2048 * 1024 + (size_t)(z - 32) * 32768; N = 32; }
  const int m0 = blockIdx.x * 64;
  const int rr = tid >> 3, c8 = (tid & 7) * 8;

  if (c8 < N) {
#pragma unroll
    for (int mm = rr; mm < 64; mm += 32) {
      const float* p = s + (size_t)(m0 + mm) * N + c8;
      float4 a = *(const float4*)p;
      float4 b = *(const float4*)(p + 4);
      T[c8 + 0][mm] = (__bf16)a.x; T[c8 + 1][mm] = (__bf16)a.y;
      T[c8 + 2][mm] = (__bf16)a.z; T[c8 + 3][mm] = (__bf16)a.w;
      T[c8 + 4][mm] = (__bf16)b.x; T[c8 + 5][mm] = (__bf16)b.y;
      T[c8 + 6][mm] = (__bf16)b.z; T[c8 + 7][mm] = (__bf16)b.w;
    }
  }
  __syncthreads();
#pragma unroll
  for (int rn = rr; rn < 64; rn += 32) {
    if (rn < N)
      *(uint4*)(d + (size_t)rn * 1024 + m0 + c8) = *(uint4*)&T[rn][c8];
  }
}

// ---------------------------------------------------------------------------
// QKV projection, m97-style: 128x128 tile, BK=64, global_load_lds width 16,
// linear LDS [128][64]. C[4096,2560] = Xb @ WcatT^T + bias, scatter epilogue.
// grid 640 (1-D, XCD-swizzled: 640%8==0 -> bijective), 256 threads.
// ---------------------------------------------------------------------------
__global__ __launch_bounds__(256) void qkv_gemm_kernel(
    const bf16_t* __restrict__ Xb, const bf16_t* __restrict__ WT,
    const float* __restrict__ bq, const float* __restrict__ bk,
    const float* __restrict__ bv,
    bf16_t* __restrict__ Qw, bf16_t* __restrict__ Kw, bf16_t* __restrict__ VT) {
  __shared__ __align__(16) bf16_t As[128 * 64];
  __shared__ __align__(16) bf16_t Bs[128 * 64];
  const int id = blockIdx.x;                  // 0..639
  const int swz = (id & 7) * 80 + (id >> 3);  // XCD-contiguous chunks
  const int m0 = (swz % 32) * 128;            // m fast -> same XCD shares B panel
  const int n0 = (swz / 32) * 128;
  const int tid = threadIdx.x;
  const int wave = tid >> 6;
  const int lane = tid & 63;
  const int wr = wave >> 1, wc = wave & 1;
  const int g = lane >> 4, ln = lane & 15;
  const int srow = lane >> 3;          // 0..7
  const int scol = (lane & 7) * 8;     // 0..56 (bf16 elems)

  f32x4 acc[4][4] = {};

  for (int k0 = 0; k0 < 1024; k0 += 64) {
#pragma unroll
    for (int c = 0; c < 4; c++) {
      const int rb = (wave * 4 + c) * 8;  // wave-uniform LDS row base
      __builtin_amdgcn_global_load_lds(
          (glb_u32*)(Xb + (size_t)(m0 + rb + srow) * 1024 + k0 + scol),
          (lds_u32*)(As + rb * 64), 16, 0, 0);
      __builtin_amdgcn_global_load_lds(
          (glb_u32*)(WT + (size_t)(n0 + rb + srow) * 1024 + k0 + scol),
          (lds_u32*)(Bs + rb * 64), 16, 0, 0);
    }
    __syncthreads();
#pragma unroll
    for (int ks = 0; ks < 2; ks++) {
      bf16x8 a[4], b[4];
#pragma unroll
      for (int m = 0; m < 4; m++)
        a[m] = *(const bf16x8*)(As + (wr * 64 + m * 16 + ln) * 64 + ks * 32 + g * 8);
#pragma unroll
      for (int n = 0; n < 4; n++)
        b[n] = *(const bf16x8*)(Bs + (wc * 64 + n * 16 + ln) * 64 + ks * 32 + g * 8);
#pragma unroll
      for (int m = 0; m < 4; m++)
#pragma unroll
        for (int n = 0; n < 4; n++)
          acc[m][n] = __builtin_amdgcn_mfma_f32_16x16x32_bf16(a[m], b[n], acc[m][n], 0, 0, 0);
    }
    __syncthreads();
  }

  const int orow = m0 + wr * 64;
  const int ocol = n0 + wc * 64;
#pragma unroll
  for (int n = 0; n < 4; n++) {
    int c = ocol + n * 16 + ln;
    float bias = (c < 1024) ? bq[c] : (c < 2048 ? bk[c - 1024] : bv[c - 2048]);
#pragma unroll
    for (int m = 0; m < 4; m++) {
#pragma unroll
      for (int i = 0; i < 4; i++) {
        int mm = orow + m * 16 + g * 4 + i;
        float v = acc[m][n][i] + bias;
        int b_ = mm >> 10, s_ = mm & 1023;
        if (c < 1024) {
          int h = c >> 6, k = c & 63;
          Qw[(((size_t)(b_ * HH + h)) * SS + s_) * DKK + k] = (__bf16)(v * 0.125f);
        } else if (c < 2048) {
          int c2 = c - 1024, h = c2 >> 6, k = c2 & 63;
          Kw[(((size_t)(b_ * HH + h)) * SS + s_) * DKK + k] = (__bf16)v;
        } else {
          int c2 = c - 2048, h = c2 >> 5, vv = c2 & 31;
          VT[(((size_t)(b_ * HH + h)) * DVV + vv) * SS + s_] = (__bf16)v;
        }
      }
    }
  }
}

// ---------------------------------------------------------------------------
// Fused scores + softmax + PV, no-max softmax, XCD-swizzled so each XCD owns
// 8 whole (b,h) heads -> K/V L2-resident across the 16 m-blocks per head.
// Weights stream (256 MB write-once) uses nontemporal stores to avoid
// evicting K/V from L2/L3. s_setprio(1) around MFMA clusters (T5).
// grid 1024 (1-D), 256 threads; each wave owns 16 rows.
// ---------------------------------------------------------------------------
__global__ __launch_bounds__(256) void attn_fused_kernel(
    const bf16_t* __restrict__ Qw, const bf16_t* __restrict__ Kw,
    const bf16_t* __restrict__ VT, float* __restrict__ Wout,
    bf16_t* __restrict__ concat) {
  __shared__ __align__(16) bf16_t Qs[64][72];
  __shared__ __align__(16) bf16_t Ks[64][72];
  __shared__ __align__(16) bf16_t Ps[64][72];
  __shared__ __align__(16) bf16_t Vs[32][72];
  const int id = blockIdx.x;                    // 0..1023
  const int swz = (id & 7) * 128 + (id >> 3);   // 8 heads per XCD
  const int bh = swz >> 4;
  const int m0 = (swz & 15) * 64;
  const int b_ = bh >> 4, h = bh & 15;
  const int tid = threadIdx.x;
  const int wave = tid >> 6;
  const int lane = tid & 63;
  const int g = lane >> 4;
  const int ln = lane & 15;
  const int r = tid >> 3;          // 0..31
  const int c8 = (tid & 7) * 8;

  const bf16_t* Qbase = Qw + (size_t)bh * SS * DKK;
  const bf16_t* Kbase = Kw + (size_t)bh * SS * DKK;
  const bf16_t* vbase = VT + (size_t)bh * DVV * SS;

  *(uint4*)&Qs[r][c8]      = *(const uint4*)(Qbase + (size_t)(m0 + r) * DKK + c8);
  *(uint4*)&Qs[r + 32][c8] = *(const uint4*)(Qbase + (size_t)(m0 + r + 32) * DKK + c8);

  float lrun[4] = {0.f, 0.f, 0.f, 0.f};

  // ---- Pass A: l = sum exp(s) ----
  uint4 ka = *(const uint4*)(Kbase + (size_t)r * DKK + c8);
  uint4 kb = *(const uint4*)(Kbase + (size_t)(r + 32) * DKK + c8);
  for (int jt = 0; jt < 16; jt++) {
    __syncthreads();  // all waves done reading Ks (prev iter) / Qs stores done
    *(uint4*)&Ks[r][c8]      = ka;   // implicit vmcnt wait on own loads
    *(uint4*)&Ks[r + 32][c8] = kb;
    if (jt + 1 < 16) {               // issue next-tile loads; land during compute
      ka = *(const uint4*)(Kbase + (size_t)((jt + 1) * 64 + r) * DKK + c8);
      kb = *(const uint4*)(Kbase + (size_t)((jt + 1) * 64 + r + 32) * DKK + c8);
    }
    __syncthreads();  // Ks tile jt ready
    f32x4 acc[4] = {};
    __builtin_amdgcn_s_setprio(1);
#pragma unroll
    for (int ks = 0; ks < 2; ks++) {
      bf16x8 a = *(const bf16x8*)&Qs[wave * 16 + ln][ks * 32 + g * 8];
#pragma unroll
      for (int ns = 0; ns < 4; ns++) {
        bf16x8 b = *(const bf16x8*)&Ks[ns * 16 + ln][ks * 32 + g * 8];
        acc[ns] = __builtin_amdgcn_mfma_f32_16x16x32_bf16(a, b, acc[ns], 0, 0, 0);
      }
    }
    __builtin_amdgcn_s_setprio(0);
#pragma unroll
    for (int ns = 0; ns < 4; ns++)
#pragma unroll
      for (int i = 0; i < 4; i++)
        lrun[i] += exp2f(acc[ns][i] * LOG2E);
  }

  // merge l across the 16 lanes sharing each row
#pragma unroll
  for (int i = 0; i < 4; i++) {
    float l = lrun[i];
#pragma unroll
    for (int d = 1; d < 16; d <<= 1) l += __shfl_xor(l, d);
    lrun[i] = 1.0f / l;
  }

  // ---- Pass B: recompute, write weights (NT), fused PV ----
  float* wbase = Wout + (size_t)bh * SS * SS;
  f32x4 acc_o[2] = {};
  ka = *(const uint4*)(Kbase + (size_t)r * DKK + c8);
  kb = *(const uint4*)(Kbase + (size_t)(r + 32) * DKK + c8);
  uint4 va = *(const uint4*)(vbase + (size_t)r * SS + c8);
  for (int jt = 0; jt < 16; jt++) {
    __syncthreads();  // all waves done reading Ks/Vs of previous iter
    *(uint4*)&Ks[r][c8]      = ka;
    *(uint4*)&Ks[r + 32][c8] = kb;
    *(uint4*)&Vs[r][c8]      = va;
    if (jt + 1 < 16) {
      ka = *(const uint4*)(Kbase + (size_t)((jt + 1) * 64 + r) * DKK + c8);
      kb = *(const uint4*)(Kbase + (size_t)((jt + 1) * 64 + r + 32) * DKK + c8);
      va = *(const uint4*)(vbase + (size_t)r * SS + (jt + 1) * 64 + c8);
    }
    __syncthreads();
    f32x4 acc[4] = {};
    __builtin_amdgcn_s_setprio(1);
#pragma unroll
    for (int ks = 0; ks < 2; ks++) {
      bf16x8 a = *(const bf16x8*)&Qs[wave * 16 + ln][ks * 32 + g * 8];
#pragma unroll
      for (int ns = 0; ns < 4; ns++) {
        bf16x8 b = *(const bf16x8*)&Ks[ns * 16 + ln][ks * 32 + g * 8];
        acc[ns] = __builtin_amdgcn_mfma_f32_16x16x32_bf16(a, b, acc[ns], 0, 0, 0);
      }
    }
    __builtin_amdgcn_s_setprio(0);
    // normalize, write fp32 weights nontemporally, stage bf16 P tile
#pragma unroll
    for (int ns = 0; ns < 4; ns++) {
      int col = jt * 64 + ns * 16 + ln;
#pragma unroll
      for (int i = 0; i < 4; i++) {
        int mr = wave * 16 + g * 4 + i;
        float w = exp2f(acc[ns][i] * LOG2E) * lrun[i];
        __builtin_nontemporal_store(w, wbase + (size_t)(m0 + mr) * SS + col);
        Ps[mr][ns * 16 + ln] = (__bf16)w;
      }
    }
    // PV: O += P(64x64) @ V(64x32). A-frags read only this wave's own rows
    // of Ps (just written by this same wave -> in-order LDS, no barrier).
    __builtin_amdgcn_s_setprio(1);
#pragma unroll
    for (int ks = 0; ks < 2; ks++) {
      bf16x8 a = *(const bf16x8*)&Ps[wave * 16 + ln][ks * 32 + g * 8];
#pragma unroll
      for (int n2 = 0; n2 < 2; n2++) {
        bf16x8 b = *(const bf16x8*)&Vs[n2 * 16 + ln][ks * 32 + g * 8];
        acc_o[n2] = __builtin_amdgcn_mfma_f32_16x16x32_bf16(a, b, acc_o[n2], 0, 0, 0);
      }
    }
    __builtin_amdgcn_s_setprio(0);
  }

  // epilogue: concat[B*S, H*DV] bf16
#pragma unroll
  for (int n2 = 0; n2 < 2; n2++) {
    int col = n2 * 16 + ln;
#pragma unroll
    for (int i = 0; i < 4; i++) {
      int s_ = m0 + wave * 16 + g * 4 + i;
      concat[((size_t)(b_ * SS + s_)) * (HH * DVV) + h * DVV + col] =
          (__bf16)acc_o[n2][i];
    }
  }
}

// ---------------------------------------------------------------------------
// Output projection, 128x64 tile (512 blocks = 2/CU; the old 128x128 grid
// was 256 blocks = 1 block/CU = 1 wave/SIMD, no latency hiding).
// out = concat @ WoT^T + bo. grid 512 (1-D, XCD-swizzled), 256 threads.
// ---------------------------------------------------------------------------
__global__ __launch_bounds__(256) void out_gemm_kernel(
    const bf16_t* __restrict__ Cc, const bf16_t* __restrict__ WoT,
    const float* __restrict__ bo, float* __restrict__ Out) {
  __shared__ __align__(16) bf16_t As[128 * 64];
  __shared__ __align__(16) bf16_t Bs[64 * 64];
  const int id = blockIdx.x;                  // 0..511
  const int swz = (id & 7) * 64 + (id >> 3);
  const int m0 = (swz & 31) * 128;            // 32 m-tiles
  const int n0 = (swz >> 5) * 64;             // 16 n-tiles
  const int tid = threadIdx.x;
  const int wave = tid >> 6;
  const int lane = tid & 63;
  const int wr = wave >> 1, wc = wave & 1;    // 64-row x 32-col wave quadrant
  const int g = lane >> 4, ln = lane & 15;
  const int srow = lane >> 3;
  const int scol = (lane & 7) * 8;

  f32x4 acc[4][2] = {};

  for (int k0 = 0; k0 < 512; k0 += 64) {
#pragma unroll
    for (int c = 0; c < 4; c++) {
      const int rb = (wave * 4 + c) * 8;
      __builtin_amdgcn_global_load_lds(
          (glb_u32*)(Cc + (size_t)(m0 + rb + srow) * 512 + k0 + scol),
          (lds_u32*)(As + rb * 64), 16, 0, 0);
    }
#pragma unroll
    for (int c = 0; c < 2; c++) {
      const int rb = (wave * 2 + c) * 8;
      __builtin_amdgcn_global_load_lds(
          (glb_u32*)(WoT + (size_t)(n0 + rb + srow) * 512 + k0 + scol),
          (lds_u32*)(Bs + rb * 64), 16, 0, 0);
    }
    __syncthreads();
#pragma unroll
    for (int ks = 0; ks < 2; ks++) {
      bf16x8 a[4], b[2];
#pragma unroll
      for (int m = 0; m < 4; m++)
        a[m] = *(const bf16x8*)(As + (wr * 64 + m * 16 + ln) * 64 + ks * 32 + g * 8);
#pragma unroll
      for (int n = 0; n < 2; n++)
        b[n] = *(const bf16x8*)(Bs + (wc * 32 + n * 16 + ln) * 64 + ks * 32 + g * 8);
#pragma unroll
      for (int m = 0; m < 4; m++)
#pragma unroll
        for (int n = 0; n < 2; n++)
          acc[m][n] = __builtin_amdgcn_mfma_f32_16x16x32_bf16(a[m], b[n], acc[m][n], 0, 0, 0);
    }
    __syncthreads();
  }

#pragma unroll
  for (int n = 0; n < 2; n++) {
    int col = n0 + wc * 32 + n * 16 + ln;
    float bias = bo[col];
#pragma unroll
    for (int m = 0; m < 4; m++) {
#pragma unroll
      for (int i = 0; i < 4; i++) {
        int mm = m0 + wr * 64 + m * 16 + g * 4 + i;
        Out[(size_t)mm * DD + col] = acc[m][n][i] + bias;
      }
    }
  }
}

// ---------------------------------------------------------------------------
extern "C" void kernel_launch(void* const* d_in, const int* in_sizes, int n_in,
                              void* d_out, int out_size, void* d_ws, size_t ws_size,
                              hipStream_t stream) {
  const float* x  = (const float*)d_in[0];
  const float* Wq = (const float*)d_in[1];
  const float* bq = (const float*)d_in[2];
  const float* Wk = (const float*)d_in[3];
  const float* bk = (const float*)d_in[4];
  const float* Wv = (const float*)d_in[5];
  const float* bv = (const float*)d_in[6];
  const float* Wo = (const float*)d_in[7];
  const float* bo = (const float*)d_in[8];

  float* out = (float*)d_out;
  float* weights_out = out + (size_t)BB * SS * DD;   // second tuple element

  // workspace (bf16, all 16B-aligned offsets); total ~30 MB (proven-safe).
  char* ws = (char*)d_ws;
  bf16_t* WcatT = (bf16_t*)ws;  ws += (size_t)2560 * 1024 * 2;        // 5 MB
  bf16_t* WoT   = (bf16_t*)ws;  ws += (size_t)1024 * 512 * 2;         // 1 MB
  bf16_t* Qw    = (bf16_t*)ws;  ws += (size_t)BB * HH * SS * DKK * 2; // 8 MB
  bf16_t* Kw    = (bf16_t*)ws;  ws += (size_t)BB * HH * SS * DKK * 2; // 8 MB
  bf16_t* VT    = (bf16_t*)ws;  ws += (size_t)BB * HH * DVV * SS * 2; // 4 MB
  bf16_t* concat = (bf16_t*)ws;                                       // 4 MB

  // Xb (8 MB bf16) stashed at the START of the weights output region:
  // consumed by qkv_gemm before attn_fused overwrites all 256 MB of weights.
  bf16_t* Xb = (bf16_t*)weights_out;

  // Weight repacks (fp32 -> bf16, transposed) + X cvt
  wqkv_transpose_kernel<<<dim3(16, 48), 256, 0, stream>>>(Wq, Wk, Wv, WcatT);
  transpose_cvt_kernel<<<dim3(16, 8, 1), 256, 0, stream>>>(
      Wo, WoT, 512, 1024, 0, 0);
  xcvt_kernel<<<1024, 256, 0, stream>>>(x, Xb);

  qkv_gemm_kernel<<<640, 256, 0, stream>>>(
      Xb, WcatT, bq, bk, bv, Qw, Kw, VT);
  attn_fused_kernel<<<1024, 256, 0, stream>>>(
      Qw, Kw, VT, weights_out, concat);
  out_gemm_kernel<<<512, 256, 0, stream>>>(concat, WoT, bo, out);
}

// Round 5
// 430.885 us; speedup vs baseline: 1.0625x; 1.0625x over previous
//
#include <hip/hip_runtime.h>
#include <cstdint>
#include <cstddef>

// Problem constants: B=4, S=1024, D=1024, H=16, DK=64, DV=32. FP32 I/O.
#define BB 4
#define SS 1024
#define DD 1024
#define HH 16
#define DKK 64
#define DVV 32
#define LOG2E 1.44269504088896340736f

typedef __bf16 bf16_t;
typedef __bf16 bf16x8 __attribute__((ext_vector_type(8)));
typedef float f32x4 __attribute__((ext_vector_type(4)));

typedef __attribute__((address_space(3))) unsigned int lds_u32;
typedef const __attribute__((address_space(1))) unsigned int glb_u32;

// load 8 consecutive fp32, convert to 8 bf16 (RNE via __bf16 cast)
__device__ inline bf16x8 cvt8(const float* __restrict__ s) {
  float4 a = *(const float4*)s;
  float4 b = *(const float4*)(s + 4);
  bf16x8 r;
  r[0] = (__bf16)a.x; r[1] = (__bf16)a.y; r[2] = (__bf16)a.z; r[3] = (__bf16)a.w;
  r[4] = (__bf16)b.x; r[5] = (__bf16)b.y; r[6] = (__bf16)b.z; r[7] = (__bf16)b.w;
  return r;
}

// ---------------------------------------------------------------------------
// Merged prep: one launch does all weight repacks + X cvt.
//   blocks [0,768)    : Wq/Wk/Wv transpose -> WcatT[2560][1024] bf16
//   blocks [768,896)  : Wo transpose -> WoT[1024][512] bf16
//   blocks [896,1920) : X fp32 -> Xb bf16 (16 elems/thread)
// 256 threads. Whole block takes one branch -> __syncthreads safe.
// ---------------------------------------------------------------------------
__global__ __launch_bounds__(256) void prep_kernel(
    const float* __restrict__ Wq, const float* __restrict__ Wk,
    const float* __restrict__ Wv, const float* __restrict__ Wo,
    const float* __restrict__ X,
    bf16_t* __restrict__ WcatT, bf16_t* __restrict__ WoT,
    bf16_t* __restrict__ Xb) {
  __shared__ __align__(16) bf16_t T[64][72];
  const int id = blockIdx.x;
  const int tid = threadIdx.x;

  if (id >= 896) {  // ---- xcvt ----
    size_t i = ((size_t)(id - 896) * 256 + tid) * 16;
    bf16x8 a = cvt8(X + i);
    bf16x8 b = cvt8(X + i + 8);
    *(bf16x8*)(Xb + i) = a;
    *(bf16x8*)(Xb + i + 8) = b;
    return;
  }

  const int rr = tid >> 3, c8 = (tid & 7) * 8;

  if (id < 768) {  // ---- Wq/Wk/Wv transpose (per-head 64x{64|32} tiles) ----
    const int m0 = (id & 15) * 64;     // row block within head matrix [1024][N]
    const int z = id >> 4;             // 0..47
    const float* s; bf16_t* d; int N;
    if (z < 16)      { s = Wq + (size_t)z * 65536;        d = WcatT + (size_t)z * 65536;                              N = 64; }
    else if (z < 32) { s = Wk + (size_t)(z - 16) * 65536; d = WcatT + (size_t)1024 * 1024 + (size_t)(z - 16) * 65536; N = 64; }
    else             { s = Wv + (size_t)(z - 32) * 32768; d = WcatT + (size_t)2048 * 1024 + (size_t)(z - 32) * 32768; N = 32; }

    if (c8 < N) {
#pragma unroll
      for (int mm = rr; mm < 64; mm += 32) {
        const float* p = s + (size_t)(m0 + mm) * N + c8;
        float4 a = *(const float4*)p;
        float4 b = *(const float4*)(p + 4);
        T[c8 + 0][mm] = (__bf16)a.x; T[c8 + 1][mm] = (__bf16)a.y;
        T[c8 + 2][mm] = (__bf16)a.z; T[c8 + 3][mm] = (__bf16)a.w;
        T[c8 + 4][mm] = (__bf16)b.x; T[c8 + 5][mm] = (__bf16)b.y;
        T[c8 + 6][mm] = (__bf16)b.z; T[c8 + 7][mm] = (__bf16)b.w;
      }
    }
    __syncthreads();
#pragma unroll
    for (int rn = rr; rn < 64; rn += 32) {
      if (rn < N)
        *(uint4*)(d + (size_t)rn * 1024 + m0 + c8) = *(uint4*)&T[rn][c8];
    }
    return;
  }

  // ---- Wo transpose: Wo[512][1024] -> WoT[1024][512] ----
  {
    const int local = id - 768;        // 0..127
    const int n0 = (local & 15) * 64;  // col block of Wo (row block of WoT)
    const int m0 = (local >> 4) * 64;  // row block of Wo
#pragma unroll
    for (int mm = rr; mm < 64; mm += 32) {
      const float* p = Wo + (size_t)(m0 + mm) * 1024 + n0 + c8;
      float4 a = *(const float4*)p;
      float4 b = *(const float4*)(p + 4);
      T[c8 + 0][mm] = (__bf16)a.x; T[c8 + 1][mm] = (__bf16)a.y;
      T[c8 + 2][mm] = (__bf16)a.z; T[c8 + 3][mm] = (__bf16)a.w;
      T[c8 + 4][mm] = (__bf16)b.x; T[c8 + 5][mm] = (__bf16)b.y;
      T[c8 + 6][mm] = (__bf16)b.z; T[c8 + 7][mm] = (__bf16)b.w;
    }
    __syncthreads();
#pragma unroll
    for (int rn = rr; rn < 64; rn += 32)
      *(uint4*)(WoT + (size_t)(n0 + rn) * 512 + m0 + c8) = *(uint4*)&T[rn][c8];
  }
}

// ---------------------------------------------------------------------------
// QKV projection, m97-style: 128x128 tile, BK=64, global_load_lds width 16,
// linear LDS [128][64]. C[4096,2560] = Xb @ WcatT^T + bias, scatter epilogue.
// grid (32, 20), 256 threads (4 waves, 2x2).
// ---------------------------------------------------------------------------
__global__ __launch_bounds__(256) void qkv_gemm_kernel(
    const bf16_t* __restrict__ Xb, const bf16_t* __restrict__ WT,
    const float* __restrict__ bq, const float* __restrict__ bk,
    const float* __restrict__ bv,
    bf16_t* __restrict__ Qw, bf16_t* __restrict__ Kw, bf16_t* __restrict__ VT) {
  __shared__ __align__(16) bf16_t As[128 * 64];
  __shared__ __align__(16) bf16_t Bs[128 * 64];
  const int tid = threadIdx.x;
  const int wave = tid >> 6;
  const int lane = tid & 63;
  const int wr = wave >> 1, wc = wave & 1;
  const int g = lane >> 4, ln = lane & 15;
  const int m0 = blockIdx.x * 128;
  const int n0 = blockIdx.y * 128;
  const int srow = lane >> 3;          // 0..7
  const int scol = (lane & 7) * 8;     // 0..56 (bf16 elems)

  f32x4 acc[4][4] = {};

  for (int k0 = 0; k0 < 1024; k0 += 64) {
#pragma unroll
    for (int c = 0; c < 4; c++) {
      const int rb = (wave * 4 + c) * 8;  // wave-uniform LDS row base
      __builtin_amdgcn_global_load_lds(
          (glb_u32*)(Xb + (size_t)(m0 + rb + srow) * 1024 + k0 + scol),
          (lds_u32*)(As + rb * 64), 16, 0, 0);
      __builtin_amdgcn_global_load_lds(
          (glb_u32*)(WT + (size_t)(n0 + rb + srow) * 1024 + k0 + scol),
          (lds_u32*)(Bs + rb * 64), 16, 0, 0);
    }
    __syncthreads();
#pragma unroll
    for (int ks = 0; ks < 2; ks++) {
      bf16x8 a[4], b[4];
#pragma unroll
      for (int m = 0; m < 4; m++)
        a[m] = *(const bf16x8*)(As + (wr * 64 + m * 16 + ln) * 64 + ks * 32 + g * 8);
#pragma unroll
      for (int n = 0; n < 4; n++)
        b[n] = *(const bf16x8*)(Bs + (wc * 64 + n * 16 + ln) * 64 + ks * 32 + g * 8);
#pragma unroll
      for (int m = 0; m < 4; m++)
#pragma unroll
        for (int n = 0; n < 4; n++)
          acc[m][n] = __builtin_amdgcn_mfma_f32_16x16x32_bf16(a[m], b[n], acc[m][n], 0, 0, 0);
    }
    __syncthreads();
  }

  const int orow = m0 + wr * 64;
  const int ocol = n0 + wc * 64;
#pragma unroll
  for (int n = 0; n < 4; n++) {
    int c = ocol + n * 16 + ln;
    float bias = (c < 1024) ? bq[c] : (c < 2048 ? bk[c - 1024] : bv[c - 2048]);
#pragma unroll
    for (int m = 0; m < 4; m++) {
#pragma unroll
      for (int i = 0; i < 4; i++) {
        int mm = orow + m * 16 + g * 4 + i;
        float v = acc[m][n][i] + bias;
        int b_ = mm >> 10, s_ = mm & 1023;
        if (c < 1024) {
          int h = c >> 6, k = c & 63;
          Qw[(((size_t)(b_ * HH + h)) * SS + s_) * DKK + k] = (__bf16)(v * 0.125f);
        } else if (c < 2048) {
          int c2 = c - 1024, h = c2 >> 6, k = c2 & 63;
          Kw[(((size_t)(b_ * HH + h)) * SS + s_) * DKK + k] = (__bf16)v;
        } else {
          int c2 = c - 2048, h = c2 >> 5, vv = c2 & 31;
          VT[(((size_t)(b_ * HH + h)) * DVV + vv) * SS + s_] = (__bf16)v;
        }
      }
    }
  }
}

// ---------------------------------------------------------------------------
// Fused scores + softmax + PV, T14 async-staged, no-max softmax.
// (R3-verified body: plain stores through L2 -- write-combining of the 64B
// row segments into full lines matters on the 256 MB weights stream; NT
// stores cost ~40 us in R4. No setprio: 4-wave lockstep = m190 null regime.)
// grid (16, 64), 256 threads; each wave owns 16 rows.
// ---------------------------------------------------------------------------
__global__ __launch_bounds__(256) void attn_fused_kernel(
    const bf16_t* __restrict__ Qw, const bf16_t* __restrict__ Kw,
    const bf16_t* __restrict__ VT, float* __restrict__ Wout,
    bf16_t* __restrict__ concat) {
  __shared__ __align__(16) bf16_t Qs[64][72];
  __shared__ __align__(16) bf16_t Ks[64][72];
  __shared__ __align__(16) bf16_t Ps[64][72];
  __shared__ __align__(16) bf16_t Vs[32][72];
  const int bh = blockIdx.y;
  const int b_ = bh >> 4, h = bh & 15;
  const int m0 = blockIdx.x * 64;
  const int tid = threadIdx.x;
  const int wave = tid >> 6;
  const int lane = tid & 63;
  const int g = lane >> 4;
  const int ln = lane & 15;
  const int r = tid >> 3;          // 0..31
  const int c8 = (tid & 7) * 8;

  const bf16_t* Qbase = Qw + (size_t)bh * SS * DKK;
  const bf16_t* Kbase = Kw + (size_t)bh * SS * DKK;
  const bf16_t* vbase = VT + (size_t)bh * DVV * SS;

  *(uint4*)&Qs[r][c8]      = *(const uint4*)(Qbase + (size_t)(m0 + r) * DKK + c8);
  *(uint4*)&Qs[r + 32][c8] = *(const uint4*)(Qbase + (size_t)(m0 + r + 32) * DKK + c8);

  float lrun[4] = {0.f, 0.f, 0.f, 0.f};

  // ---- Pass A: l = sum exp(s) ----
  uint4 ka = *(const uint4*)(Kbase + (size_t)r * DKK + c8);
  uint4 kb = *(const uint4*)(Kbase + (size_t)(r + 32) * DKK + c8);
  for (int jt = 0; jt < 16; jt++) {
    __syncthreads();  // all waves done reading Ks (prev iter) / Qs stores done
    *(uint4*)&Ks[r][c8]      = ka;   // implicit vmcnt wait on own loads
    *(uint4*)&Ks[r + 32][c8] = kb;
    if (jt + 1 < 16) {               // issue next-tile loads; land during compute
      ka = *(const uint4*)(Kbase + (size_t)((jt + 1) * 64 + r) * DKK + c8);
      kb = *(const uint4*)(Kbase + (size_t)((jt + 1) * 64 + r + 32) * DKK + c8);
    }
    __syncthreads();  // Ks tile jt ready
    f32x4 acc[4] = {};
#pragma unroll
    for (int ks = 0; ks < 2; ks++) {
      bf16x8 a = *(const bf16x8*)&Qs[wave * 16 + ln][ks * 32 + g * 8];
#pragma unroll
      for (int ns = 0; ns < 4; ns++) {
        bf16x8 b = *(const bf16x8*)&Ks[ns * 16 + ln][ks * 32 + g * 8];
        acc[ns] = __builtin_amdgcn_mfma_f32_16x16x32_bf16(a, b, acc[ns], 0, 0, 0);
      }
    }
#pragma unroll
    for (int ns = 0; ns < 4; ns++)
#pragma unroll
      for (int i = 0; i < 4; i++)
        lrun[i] += exp2f(acc[ns][i] * LOG2E);
  }

  // merge l across the 16 lanes sharing each row
#pragma unroll
  for (int i = 0; i < 4; i++) {
    float l = lrun[i];
#pragma unroll
    for (int d = 1; d < 16; d <<= 1) l += __shfl_xor(l, d);
    lrun[i] = 1.0f / l;
  }

  // ---- Pass B: recompute, write weights, fused PV ----
  float* wbase = Wout + (size_t)bh * SS * SS;
  f32x4 acc_o[2] = {};
  ka = *(const uint4*)(Kbase + (size_t)r * DKK + c8);
  kb = *(const uint4*)(Kbase + (size_t)(r + 32) * DKK + c8);
  uint4 va = *(const uint4*)(vbase + (size_t)r * SS + c8);
  for (int jt = 0; jt < 16; jt++) {
    __syncthreads();  // all waves done reading Ks/Vs of previous iter
    *(uint4*)&Ks[r][c8]      = ka;
    *(uint4*)&Ks[r + 32][c8] = kb;
    *(uint4*)&Vs[r][c8]      = va;
    if (jt + 1 < 16) {
      ka = *(const uint4*)(Kbase + (size_t)((jt + 1) * 64 + r) * DKK + c8);
      kb = *(const uint4*)(Kbase + (size_t)((jt + 1) * 64 + r + 32) * DKK + c8);
      va = *(const uint4*)(vbase + (size_t)r * SS + (jt + 1) * 64 + c8);
    }
    __syncthreads();
    f32x4 acc[4] = {};
#pragma unroll
    for (int ks = 0; ks < 2; ks++) {
      bf16x8 a = *(const bf16x8*)&Qs[wave * 16 + ln][ks * 32 + g * 8];
#pragma unroll
      for (int ns = 0; ns < 4; ns++) {
        bf16x8 b = *(const bf16x8*)&Ks[ns * 16 + ln][ks * 32 + g * 8];
        acc[ns] = __builtin_amdgcn_mfma_f32_16x16x32_bf16(a, b, acc[ns], 0, 0, 0);
      }
    }
    // normalize, write fp32 weights, stage bf16 P tile (own wave's rows)
#pragma unroll
    for (int ns = 0; ns < 4; ns++) {
      int col = jt * 64 + ns * 16 + ln;
#pragma unroll
      for (int i = 0; i < 4; i++) {
        int mr = wave * 16 + g * 4 + i;
        float w = exp2f(acc[ns][i] * LOG2E) * lrun[i];
        wbase[(size_t)(m0 + mr) * SS + col] = w;
        Ps[mr][ns * 16 + ln] = (__bf16)w;
      }
    }
    // PV: O += P(64x64) @ V(64x32). A-frags read only this wave's own rows
    // of Ps (just written by this same wave -> in-order LDS, no barrier).
#pragma unroll
    for (int ks = 0; ks < 2; ks++) {
      bf16x8 a = *(const bf16x8*)&Ps[wave * 16 + ln][ks * 32 + g * 8];
#pragma unroll
      for (int n2 = 0; n2 < 2; n2++) {
        bf16x8 b = *(const bf16x8*)&Vs[n2 * 16 + ln][ks * 32 + g * 8];
        acc_o[n2] = __builtin_amdgcn_mfma_f32_16x16x32_bf16(a, b, acc_o[n2], 0, 0, 0);
      }
    }
  }

  // epilogue: concat[B*S, H*DV] bf16
#pragma unroll
  for (int n2 = 0; n2 < 2; n2++) {
    int col = n2 * 16 + ln;
#pragma unroll
    for (int i = 0; i < 4; i++) {
      int s_ = m0 + wave * 16 + g * 4 + i;
      concat[((size_t)(b_ * SS + s_)) * (HH * DVV) + h * DVV + col] =
          (__bf16)acc_o[n2][i];
    }
  }
}

// ---------------------------------------------------------------------------
// Output projection, 128x64 tile (512 blocks = 2 blocks/CU; a 128x128 grid
// is only 256 blocks = 1 block/CU = no inter-block overlap of the 2-barrier
// loop). out = concat @ WoT^T + bo. grid (32, 16), 256 threads. K = 512.
// ---------------------------------------------------------------------------
__global__ __launch_bounds__(256) void out_gemm_kernel(
    const bf16_t* __restrict__ Cc, const bf16_t* __restrict__ WoT,
    const float* __restrict__ bo, float* __restrict__ Out) {
  __shared__ __align__(16) bf16_t As[128 * 64];
  __shared__ __align__(16) bf16_t Bs[64 * 64];
  const int m0 = blockIdx.x * 128;
  const int n0 = blockIdx.y * 64;
  const int tid = threadIdx.x;
  const int wave = tid >> 6;
  const int lane = tid & 63;
  const int wr = wave >> 1, wc = wave & 1;    // 64-row x 32-col wave quadrant
  const int g = lane >> 4, ln = lane & 15;
  const int srow = lane >> 3;
  const int scol = (lane & 7) * 8;

  f32x4 acc[4][2] = {};

  for (int k0 = 0; k0 < 512; k0 += 64) {
#pragma unroll
    for (int c = 0; c < 4; c++) {
      const int rb = (wave * 4 + c) * 8;
      __builtin_amdgcn_global_load_lds(
          (glb_u32*)(Cc + (size_t)(m0 + rb + srow) * 512 + k0 + scol),
          (lds_u32*)(As + rb * 64), 16, 0, 0);
    }
#pragma unroll
    for (int c = 0; c < 2; c++) {
      const int rb = (wave * 2 + c) * 8;
      __builtin_amdgcn_global_load_lds(
          (glb_u32*)(WoT + (size_t)(n0 + rb + srow) * 512 + k0 + scol),
          (lds_u32*)(Bs + rb * 64), 16, 0, 0);
    }
    __syncthreads();
#pragma unroll
    for (int ks = 0; ks < 2; ks++) {
      bf16x8 a[4], b[2];
#pragma unroll
      for (int m = 0; m < 4; m++)
        a[m] = *(const bf16x8*)(As + (wr * 64 + m * 16 + ln) * 64 + ks * 32 + g * 8);
#pragma unroll
      for (int n = 0; n < 2; n++)
        b[n] = *(const bf16x8*)(Bs + (wc * 32 + n * 16 + ln) * 64 + ks * 32 + g * 8);
#pragma unroll
      for (int m = 0; m < 4; m++)
#pragma unroll
        for (int n = 0; n < 2; n++)
          acc[m][n] = __builtin_amdgcn_mfma_f32_16x16x32_bf16(a[m], b[n], acc[m][n], 0, 0, 0);
    }
    __syncthreads();
  }

#pragma unroll
  for (int n = 0; n < 2; n++) {
    int col = n0 + wc * 32 + n * 16 + ln;
    float bias = bo[col];
#pragma unroll
    for (int m = 0; m < 4; m++) {
#pragma unroll
      for (int i = 0; i < 4; i++) {
        int mm = m0 + wr * 64 + m * 16 + g * 4 + i;
        Out[(size_t)mm * DD + col] = acc[m][n][i] + bias;
      }
    }
  }
}

// ---------------------------------------------------------------------------
extern "C" void kernel_launch(void* const* d_in, const int* in_sizes, int n_in,
                              void* d_out, int out_size, void* d_ws, size_t ws_size,
                              hipStream_t stream) {
  const float* x  = (const float*)d_in[0];
  const float* Wq = (const float*)d_in[1];
  const float* bq = (const float*)d_in[2];
  const float* Wk = (const float*)d_in[3];
  const float* bk = (const float*)d_in[4];
  const float* Wv = (const float*)d_in[5];
  const float* bv = (const float*)d_in[6];
  const float* Wo = (const float*)d_in[7];
  const float* bo = (const float*)d_in[8];

  float* out = (float*)d_out;
  float* weights_out = out + (size_t)BB * SS * DD;   // second tuple element

  // workspace (bf16, all 16B-aligned offsets); total ~30 MB (proven-safe).
  char* ws = (char*)d_ws;
  bf16_t* WcatT = (bf16_t*)ws;  ws += (size_t)2560 * 1024 * 2;        // 5 MB
  bf16_t* WoT   = (bf16_t*)ws;  ws += (size_t)1024 * 512 * 2;         // 1 MB
  bf16_t* Qw    = (bf16_t*)ws;  ws += (size_t)BB * HH * SS * DKK * 2; // 8 MB
  bf16_t* Kw    = (bf16_t*)ws;  ws += (size_t)BB * HH * SS * DKK * 2; // 8 MB
  bf16_t* VT    = (bf16_t*)ws;  ws += (size_t)BB * HH * DVV * SS * 2; // 4 MB
  bf16_t* concat = (bf16_t*)ws;                                       // 4 MB

  // Xb (8 MB bf16) stashed at the START of the weights output region:
  // consumed by qkv_gemm before attn_fused overwrites all 256 MB of weights.
  bf16_t* Xb = (bf16_t*)weights_out;

  prep_kernel<<<1920, 256, 0, stream>>>(Wq, Wk, Wv, Wo, x, WcatT, WoT, Xb);
  qkv_gemm_kernel<<<dim3(32, 20), 256, 0, stream>>>(
      Xb, WcatT, bq, bk, bv, Qw, Kw, VT);
  attn_fused_kernel<<<dim3(16, 64), 256, 0, stream>>>(
      Qw, Kw, VT, weights_out, concat);
  out_gemm_kernel<<<dim3(32, 16), 256, 0, stream>>>(concat, WoT, bo, out);
}